// Round 4
// baseline (103.018 us; speedup 1.0000x reference)
//
#include <hip/hip_runtime.h>

// Chamfer distance, B=8, N=M=8192, D=3, fp32 — R15: barrier-free streaming
// + accumulator PING-PONG (fold step j-1's accs under step j's MFMAs).
//
// dist[i][j] = nx_i + ny_j - 2 x_i.y_j; out = mean(min_j) + mean(min_i).
// K=16 bf16-split packing (validated R8-R14, absmax 0.0):
//   A row = [ah0 ah1 ah2 ah0 ah1 ah2 al0 al1 | al2 nxh nxl 1 1 0 0 0]
//   B col = [yh0 yh1 yh2 yl0 yl1 yl2 yh0 yh1 | yh2 1 1 nyh nyl 0 0 0]
//
// R11-R14 post-mortem: MfmaUtil*dur == 13.5us MFMA floor in ALL variants;
// per-wave duty ~13%. The immediate min3 fold after each MFMA quartet
// forces an MFMA-latency wait AND lets the compiler keep only one acc set
// (52 VGPR reported) -> serialize issue/wait/fold/load. R15: ping-pong acc
// sets: fold previous iteration's accs (guaranteed ready) while current
// MFMAs execute; loads one pair ahead; full unroll -> compile-time offsets
// and deep load hoisting. Per-iter serial ~210cy for 129cy matrix issue
// -> duty ~60%, x3 waves/SIMD -> matrix saturation regime.

#define B_ 8
#define N_ 8192
#define PTS (B_ * N_)            // 65536 points per cloud
#define ROWS_TOTAL (2 * PTS)     // 131072 row-min slots (both directions)
#define NTILES 2048              // 32-point tiles per cloud (65536/32)
#define TPB 256

typedef short bf16x8 __attribute__((ext_vector_type(8)));
typedef float f32x16 __attribute__((ext_vector_type(16)));

__device__ __forceinline__ unsigned b16(float f) {   // fp32 -> bf16 bits (RNE)
  unsigned u = __float_as_uint(f);
  return (u + 0x7FFFu + ((u >> 16) & 1u)) >> 16;
}
__device__ __forceinline__ float bf(unsigned h) { return __uint_as_float(h << 16); }

// ---- one-shot fragment packing: 262144 tasks (A/B x dir x 65536 points) ----
__global__ __launch_bounds__(256) void pack_frags_k(
    const float* __restrict__ x, const float* __restrict__ y,
    uint4* __restrict__ afrag, uint4* __restrict__ bfrag) {
  const unsigned one = 0x3F80u;
  int t = blockIdx.x * 256 + threadIdx.x;   // 0 .. 262143
  int kind = t >> 17;                        // 0 = A-frag, 1 = B-frag
  int dir = (t >> 16) & 1;                   // 0: rows=x scan y; 1: rows=y scan x
  int p = t & 65535;
  int tile = dir * NTILES + (p >> 5), m = p & 31;
  if (kind == 0) {
    const float* src = dir ? y : x;          // row ("own") cloud
    const float* po = src + 3 * p;
    float v0 = po[0], v1 = po[1], v2 = po[2];
    float nv = fmaf(v0, v0, fmaf(v1, v1, v2 * v2));
    float a0 = -2.0f * v0, a1 = -2.0f * v1, a2 = -2.0f * v2;
    unsigned ah0 = b16(a0), ah1 = b16(a1), ah2 = b16(a2);
    unsigned al0 = b16(a0 - bf(ah0)), al1 = b16(a1 - bf(ah1)), al2 = b16(a2 - bf(ah2));
    unsigned nh = b16(nv), nl = b16(nv - bf(nh));
    afrag[tile * 64 + m]      = make_uint4(ah0 | (ah1 << 16), ah2 | (ah0 << 16),
                                           ah1 | (ah2 << 16), al0 | (al1 << 16));
    afrag[tile * 64 + 32 + m] = make_uint4(al2 | (nh << 16), nl | (one << 16), one, 0u);
  } else {
    const float* src = dir ? x : y;          // candidate cloud
    const float* pc = src + 3 * p;
    float c0 = pc[0], c1 = pc[1], c2 = pc[2];
    float nc = fmaf(c0, c0, fmaf(c1, c1, c2 * c2));
    unsigned yh0 = b16(c0), yh1 = b16(c1), yh2 = b16(c2);
    unsigned yl0 = b16(c0 - bf(yh0)), yl1 = b16(c1 - bf(yh1)), yl2 = b16(c2 - bf(yh2));
    unsigned nh = b16(nc), nl = b16(nc - bf(nh));
    bfrag[tile * 64 + m]      = make_uint4(yh0 | (yh1 << 16), yh2 | (yl0 << 16),
                                           yl1 | (yl2 << 16), yh0 | (yh1 << 16));
    bfrag[tile * 64 + 32 + m] = make_uint4(yh2 | (one << 16), one | (nh << 16), nl, 0u);
  }
}

// ---- main: 2048 blocks x 256 thr; no LDS, no barriers ----
// block = 4 waves x 64 rows = 256 rows, scans one candidate quarter (2048).
__global__ __launch_bounds__(TPB, 3) void chamfer_main_k(
    const uint4* __restrict__ afrag, const uint4* __restrict__ bfrag,
    float* __restrict__ gpart) {
  int t = threadIdx.x, lane = t & 63, w = t >> 6;    // 4 waves
  int b0 = blockIdx.x;
  // XCD-bijective swizzle (2048 blocks % 8 == 0): each XCD gets 256
  // consecutive effective ids = 2 full (dir,batch) families -> ~512KB L2 set.
  int eff = ((b0 & 7) << 8) | (b0 >> 3);
  int q = eff & 3;                 // candidate quarter (64 B-tiles)
  int rg = eff >> 2;               // 0..511 : 256-row groups
  int dir = rg >> 8;
  int batch = (rg >> 5) & 7;
  int rb = rg & 31;                // 256-row block within batch

  // A-frags: 2 row-tiles (64 rows) per wave, straight from prepacked global.
  int tileA0 = dir * NTILES + batch * 256 + rb * 8 + w * 2;
  bf16x8 A0 = __builtin_bit_cast(bf16x8, afrag[tileA0 * 64 + lane]);
  bf16x8 A1 = __builtin_bit_cast(bf16x8, afrag[(tileA0 + 1) * 64 + lane]);

  const uint4* bt = bfrag + (size_t)(dir * NTILES + batch * 256 + q * 64) * 64 + lane;

  f32x16 z, rm0, rm1;
#pragma unroll
  for (int r = 0; r < 16; ++r) { z[r] = 0.0f; rm0[r] = 1e30f; rm1[r] = 1e30f; }

#define LD(ti) __builtin_bit_cast(bf16x8, bt[(ti) * 64])
#define MF(Aa, Bb) __builtin_amdgcn_mfma_f32_32x32x16_bf16(Aa, Bb, z, 0, 0, 0)

  // ---- software pipeline with acc ping-pong ----
  bf16x8 B0v = LD(0), B1v = LD(1);           // current pair
  bf16x8 N0v = LD(2), N1v = LD(3);           // next pair
  f32x16 pP0 = MF(A0, B0v), pP1 = MF(A0, B1v);   // in-flight set P (rows A0)
  f32x16 qQ0 = MF(A1, B0v), qQ1 = MF(A1, B1v);   // in-flight set Q (rows A1)
  B0v = N0v; B1v = N1v;

#pragma unroll
  for (int j = 2; j < 64; j += 2) {          // 31 iterations, fully unrolled
    bf16x8 n0, n1;
    if (j < 62) { n0 = LD(j + 2); n1 = LD(j + 3); }
    // issue current MFMAs, then fold PREVIOUS iteration's accs (ready).
    f32x16 tP0 = MF(A0, B0v), tP1 = MF(A0, B1v);
#pragma unroll
    for (int r = 0; r < 16; ++r)
      rm0[r] = fminf(fminf(rm0[r], pP0[r]), pP1[r]);   // v_min3_f32
    f32x16 tQ0 = MF(A1, B0v), tQ1 = MF(A1, B1v);
#pragma unroll
    for (int r = 0; r < 16; ++r)
      rm1[r] = fminf(fminf(rm1[r], qQ0[r]), qQ1[r]);   // v_min3_f32
    pP0 = tP0; pP1 = tP1; qQ0 = tQ0; qQ1 = tQ1;        // rename (unrolled)
    if (j < 62) { B0v = n0; B1v = n1; }
  }
  // drain the last in-flight sets
#pragma unroll
  for (int r = 0; r < 16; ++r) {
    rm0[r] = fminf(fminf(rm0[r], pP0[r]), pP1[r]);
    rm1[r] = fminf(fminf(rm1[r], qQ0[r]), qQ1[r]);
  }
#undef LD
#undef MF

  // ---- epilogue: fold 32 cols per half (butterfly), store row-mins ----
#pragma unroll
  for (int msk = 1; msk <= 16; msk <<= 1)
#pragma unroll
    for (int r = 0; r < 16; ++r) {
      rm0[r] = fminf(rm0[r], __shfl_xor(rm0[r], msk, 64));
      rm1[r] = fminf(rm1[r], __shfl_xor(rm1[r], msk, 64));
    }

  int rowbase = dir * PTS + batch * N_ + rb * 256 + w * 64;
  float* gp = gpart + q * ROWS_TOTAL + rowbase;
  if ((lane & 31) == 0) {                      // lanes 0 and 32 (h = lane>>5)
    int h = lane >> 5;
#pragma unroll
    for (int r = 0; r < 16; ++r) {
      int rr = (r & 3) + 8 * (r >> 2) + 4 * h;
      gp[rr] = rm0[r];
      gp[32 + rr] = rm1[r];
    }
  }
}

// ---- final: min the 4 candidate-quarter partials, sum everything ----
__global__ __launch_bounds__(256) void chamfer_final_k(
    const float* __restrict__ gpart, float* __restrict__ out) {
  int i = blockIdx.x * 256 + threadIdx.x;    // 32768 threads x 4 rows (float4)
  const float4* g4 = reinterpret_cast<const float4*>(gpart);
  float4 a = g4[i];
  float4 b = g4[i + (ROWS_TOTAL / 4)];
  float4 c = g4[i + 2 * (ROWS_TOTAL / 4)];
  float4 d = g4[i + 3 * (ROWS_TOTAL / 4)];
  float s = fminf(fminf(a.x, b.x), fminf(c.x, d.x))
          + fminf(fminf(a.y, b.y), fminf(c.y, d.y))
          + fminf(fminf(a.z, b.z), fminf(c.z, d.z))
          + fminf(fminf(a.w, b.w), fminf(c.w, d.w));
  for (int off = 32; off > 0; off >>= 1) s += __shfl_down(s, off, 64);
  __shared__ float red[4];
  int lane = threadIdx.x & 63, wv = threadIdx.x >> 6;
  if (lane == 0) red[wv] = s;
  __syncthreads();
  if (threadIdx.x == 0) {
    float tt = (red[0] + red[1]) + (red[2] + red[3]);
    atomicAdd(out, tt * (1.0f / (float)PTS));
  }
}

extern "C" void kernel_launch(void* const* d_in, const int* in_sizes, int n_in,
                              void* d_out, int out_size, void* d_ws, size_t ws_size,
                              hipStream_t stream) {
  const float* x = (const float*)d_in[0];
  const float* y = (const float*)d_in[1];
  float* out = (float*)d_out;
  // ws layout: gpart 2MB | afrag 4MB | bfrag 4MB  (10MB total)
  float* gpart = (float*)d_ws;
  uint4* afrag = (uint4*)((char*)d_ws + (size_t)4 * ROWS_TOTAL * sizeof(float));
  uint4* bfrag = afrag + (size_t)2 * NTILES * 64;

  hipMemsetAsync(out, 0, sizeof(float), stream);
  pack_frags_k<<<1024, 256, 0, stream>>>(x, y, afrag, bfrag);
  chamfer_main_k<<<2048, TPB, 0, stream>>>(afrag, bfrag, gpart);
  chamfer_final_k<<<128, 256, 0, stream>>>(gpart, out);
}